// Round 2
// baseline (58.993 us; speedup 1.0000x reference)
//
#include <hip/hip_runtime.h>

#define NROWS 8192
#define NCOLS 2048
#define ROWS_PER_BLOCK 8
#define BLOCK 256
#define NSLOTS 16

// Kernel 1: partial column sums of (fx - ft).
// Grid: x = 2 column-halves (256 float4 cols each), y = 1024 row-chunks of 8.
// 2048 blocks -> 8 blocks/CU. Each thread: 8 rows x 2 arrays = 16 float4
// loads, fully unrolled for ILP. Per-column atomics are spread over 16 slots
// to cap same-address contention at 1024/16 = 64.
__global__ void __launch_bounds__(BLOCK)
colsum_kernel(const float* __restrict__ fx, const float* __restrict__ ft,
              float* __restrict__ part) {
    const int col4 = blockIdx.x * BLOCK + threadIdx.x;   // float4 column index
    const int row0 = blockIdx.y * ROWS_PER_BLOCK;
    const int stride4 = NCOLS / 4;                       // 512

    const float4* fx4 = reinterpret_cast<const float4*>(fx);
    const float4* ft4 = reinterpret_cast<const float4*>(ft);

    float4 acc = make_float4(0.f, 0.f, 0.f, 0.f);
    #pragma unroll
    for (int r = 0; r < ROWS_PER_BLOCK; ++r) {
        const int idx = (row0 + r) * stride4 + col4;
        float4 a = fx4[idx];
        float4 b = ft4[idx];
        acc.x += a.x - b.x;
        acc.y += a.y - b.y;
        acc.z += a.z - b.z;
        acc.w += a.w - b.w;
    }
    const int slot = blockIdx.y & (NSLOTS - 1);
    float* dst = part + slot * NCOLS + col4 * 4;
    atomicAdd(dst + 0, acc.x);
    atomicAdd(dst + 1, acc.y);
    atomicAdd(dst + 2, acc.z);
    atomicAdd(dst + 3, acc.w);
}

// Kernel 2: out = sum_k (sum_slots part[s][k])^2 / N^2  (single block)
__global__ void __launch_bounds__(BLOCK)
finalize_kernel(const float* __restrict__ part, float* __restrict__ out) {
    __shared__ float red[BLOCK / 64];
    const int tid = threadIdx.x;

    float acc = 0.f;
    for (int k = tid; k < NCOLS; k += BLOCK) {
        float s = 0.f;
        #pragma unroll
        for (int sl = 0; sl < NSLOTS; ++sl)
            s += part[sl * NCOLS + k];
        acc += s * s;
    }
    // 64-lane wave reduction
    #pragma unroll
    for (int off = 32; off > 0; off >>= 1)
        acc += __shfl_down(acc, off, 64);
    if ((tid & 63) == 0) red[tid >> 6] = acc;
    __syncthreads();
    if (tid == 0) {
        float tot = 0.f;
        #pragma unroll
        for (int w = 0; w < BLOCK / 64; ++w) tot += red[w];
        const double inv_n2 = 1.0 / ((double)NROWS * (double)NROWS);
        out[0] = (float)((double)tot * inv_n2);
    }
}

extern "C" void kernel_launch(void* const* d_in, const int* in_sizes, int n_in,
                              void* d_out, int out_size, void* d_ws, size_t ws_size,
                              hipStream_t stream) {
    const float* fx = (const float*)d_in[0];
    const float* ft = (const float*)d_in[1];
    float* out = (float*)d_out;
    float* part = (float*)d_ws;   // NSLOTS * NCOLS floats = 128 KiB

    // ws is poisoned (0xAA) once and never re-poisoned between replays —
    // zero it every call so accumulation starts clean.
    hipMemsetAsync(part, 0, NSLOTS * NCOLS * sizeof(float), stream);

    dim3 grid1(NCOLS / 4 / BLOCK, NROWS / ROWS_PER_BLOCK);   // 2 x 1024 = 2048 blocks
    colsum_kernel<<<grid1, BLOCK, 0, stream>>>(fx, ft, part);

    finalize_kernel<<<1, BLOCK, 0, stream>>>(part, out);
}

// Round 3
// 37.183 us; speedup vs baseline: 1.5865x; 1.5865x over previous
//
#include <hip/hip_runtime.h>

#define NROWS 8192
#define NCOLS 2048
#define ROWS_PER_BLOCK 32
#define BLOCK 256
// Stage-1 grid: x = 2 column halves, y = 256 row chunks, z = 2 arrays (fx, ft)
// slots = z*256 + y : 512 partial rows of 2048 cols = 4 MB in ws, no atomics.
#define NSLOT_PER_ARR (NROWS / ROWS_PER_BLOCK)   // 256
#define NSLOTS (2 * NSLOT_PER_ARR)               // 512
#define NQUARTER 4                               // stage-2 splits slots into 4 groups of 128

// Stage 1: per-block partial column sums, plain float4 stores (no atomics).
__global__ void __launch_bounds__(BLOCK)
colsum_part_kernel(const float* __restrict__ fx, const float* __restrict__ ft,
                   float* __restrict__ part) {
    const int col4 = blockIdx.x * BLOCK + threadIdx.x;   // float4 column 0..511
    const int row0 = blockIdx.y * ROWS_PER_BLOCK;
    const int arr  = blockIdx.z;                         // 0 = fx, 1 = ft
    const int stride4 = NCOLS / 4;                       // 512

    const float4* src = reinterpret_cast<const float4*>(arr ? ft : fx);

    float4 acc = make_float4(0.f, 0.f, 0.f, 0.f);
    #pragma unroll 16
    for (int r = 0; r < ROWS_PER_BLOCK; ++r) {
        float4 a = src[(row0 + r) * stride4 + col4];
        acc.x += a.x; acc.y += a.y; acc.z += a.z; acc.w += a.w;
    }
    const int slot = arr * NSLOT_PER_ARR + blockIdx.y;
    float4* dst = reinterpret_cast<float4*>(part + slot * NCOLS) + col4;
    *dst = acc;   // coalesced, block-private — deterministic
}

// Stage 2: reduce 512 slots -> 4 quarter-sums per column.
// 32 blocks x 256 threads = 8192 threads = 2048 cols x 4 quarters.
__global__ void __launch_bounds__(BLOCK)
reduce_quarters_kernel(const float* __restrict__ part, float* __restrict__ sq) {
    const int gtid = blockIdx.x * BLOCK + threadIdx.x;
    const int k = gtid & (NCOLS - 1);        // column
    const int q = gtid >> 11;                // quarter 0..3 (q<2: fx, q>=2: ft)
    const int s0 = q * (NSLOTS / NQUARTER);  // 128 slots per quarter

    float s = 0.f;
    #pragma unroll 8
    for (int sl = 0; sl < NSLOTS / NQUARTER; ++sl)
        s += part[(s0 + sl) * NCOLS + k];
    sq[q * NCOLS + k] = s;
}

// Stage 3: s[k] = (q0+q1) - (q2+q3); out = sum s^2 / N^2. Single block.
__global__ void __launch_bounds__(BLOCK)
finalize_kernel(const float* __restrict__ sq, float* __restrict__ out) {
    __shared__ float red[BLOCK / 64];
    const int tid = threadIdx.x;

    float acc = 0.f;
    for (int k = tid; k < NCOLS; k += BLOCK) {
        const float s = (sq[k] + sq[NCOLS + k]) - (sq[2 * NCOLS + k] + sq[3 * NCOLS + k]);
        acc += s * s;
    }
    #pragma unroll
    for (int off = 32; off > 0; off >>= 1)
        acc += __shfl_down(acc, off, 64);
    if ((tid & 63) == 0) red[tid >> 6] = acc;
    __syncthreads();
    if (tid == 0) {
        float tot = 0.f;
        #pragma unroll
        for (int w = 0; w < BLOCK / 64; ++w) tot += red[w];
        const double inv_n2 = 1.0 / ((double)NROWS * (double)NROWS);
        out[0] = (float)((double)tot * inv_n2);
    }
}

extern "C" void kernel_launch(void* const* d_in, const int* in_sizes, int n_in,
                              void* d_out, int out_size, void* d_ws, size_t ws_size,
                              hipStream_t stream) {
    const float* fx = (const float*)d_in[0];
    const float* ft = (const float*)d_in[1];
    float* out = (float*)d_out;
    float* part = (float*)d_ws;                    // 512 * 2048 floats = 4 MB
    float* sq   = part + NSLOTS * NCOLS;           // 4 * 2048 floats = 32 KB

    // No memset needed: every ws location is written before it is read.
    dim3 grid1(NCOLS / 4 / BLOCK, NSLOT_PER_ARR, 2);   // 2 x 256 x 2 = 1024 blocks
    colsum_part_kernel<<<grid1, BLOCK, 0, stream>>>(fx, ft, part);

    reduce_quarters_kernel<<<NQUARTER * NCOLS / BLOCK, BLOCK, 0, stream>>>(part, sq);

    finalize_kernel<<<1, BLOCK, 0, stream>>>(sq, out);
}